// Round 2
// baseline (131.023 us; speedup 1.0000x reference)
//
#include <hip/hip_runtime.h>
#include <hip/hip_bf16.h>

#define BB 4
#define NN 512
#define CC 32
#define KK 4      // K+1
#define HH 4
#define AOUT 256

// ---------------------------------------------------------------------------
// Kernel A: per (b,n) compute si_re, si_im, sj_re, sj_im  (each B*N*H floats)
// ws layout: [0,8192) si_re | [8192,16384) si_im | [16384,24576) sj_re | [24576,32768) sj_im  (floats)
// ---------------------------------------------------------------------------
__global__ __launch_bounds__(256) void precompute_s_kernel(
    const float* __restrict__ Xr, const float* __restrict__ Xi,
    const float* __restrict__ AWr, const float* __restrict__ AWi,
    float* __restrict__ ws)
{
    int idx = blockIdx.x * blockDim.x + threadIdx.x;
    if (idx >= BB * NN) return;
    const float* xr = Xr + (size_t)idx * CC;
    const float* xi = Xi + (size_t)idx * CC;
    float sir[HH] = {0,0,0,0}, sii[HH] = {0,0,0,0};
    float sjr[HH] = {0,0,0,0}, sji[HH] = {0,0,0,0};
    for (int c = 0; c < CC; ++c) {
        float xrc = xr[c], xic = xi[c];
        const float* w1r = AWr + c*HH;
        const float* w1i = AWi + c*HH;
        const float* w2r = AWr + (CC + c)*HH;
        const float* w2i = AWi + (CC + c)*HH;
        #pragma unroll
        for (int h = 0; h < HH; ++h) {
            sir[h] = fmaf(xrc, w1r[h], fmaf(-xic, w1i[h], sir[h]));
            sii[h] = fmaf(xrc, w1i[h], fmaf( xic, w1r[h], sii[h]));
            sjr[h] = fmaf(xrc, w2r[h], fmaf(-xic, w2i[h], sjr[h]));
            sji[h] = fmaf(xrc, w2i[h], fmaf( xic, w2r[h], sji[h]));
        }
    }
    float* si_re = ws;
    float* si_im = ws +     BB*NN*HH;
    float* sj_re = ws + 2 * BB*NN*HH;
    float* sj_im = ws + 3 * BB*NN*HH;
    #pragma unroll
    for (int h = 0; h < HH; ++h) {
        si_re[idx*HH + h] = sir[h];
        si_im[idx*HH + h] = sii[h];
        sj_re[idx*HH + h] = sjr[h];
        sj_im[idx*HH + h] = sji[h];
    }
}

// ---------------------------------------------------------------------------
// Kernel B: one block per (b,n). 128 threads.
//   phase 1: stage L_real/L_imag rows [k][j] into LDS (coalesced float4)
//   phase 2: scores + mask + softmax over j (unnormalized exp kept in LDS)
//   phase 3: LX accumulation; thread = (c-pair, h, j-half), 16 accumulators
//   phase 4: contract with weights, write fp32 out (+bias)
// ---------------------------------------------------------------------------
__global__ __launch_bounds__(128) void cheb_main_kernel(
    const float* __restrict__ Xr, const float* __restrict__ Xi,
    const float* __restrict__ Lr_g, const float* __restrict__ Li_g,
    const float* __restrict__ Wr_g, const float* __restrict__ Wi_g,
    const float* __restrict__ abr, const float* __restrict__ abi,
    const float* __restrict__ par, const float* __restrict__ pai,
    const float* __restrict__ bsr, const float* __restrict__ bsi,
    const float* __restrict__ ws,
    float* __restrict__ out)
{
    __shared__ float Lr[KK][NN];      // 8 KB
    __shared__ float Li[KK][NN];      // 8 KB
    __shared__ float aw[NN][HH];      // 8 KB  scores -> exp values
    __shared__ float red[HH][128];    // 2 KB
    __shared__ float part[64][17];    // 4.25 KB (padded: no bank conflict)
    __shared__ float LXr[KK][CC][HH]; // 2 KB
    __shared__ float LXi[KK][CC][HH]; // 2 KB
    __shared__ float hmax[HH], hsum[HH];

    const int bn = blockIdx.x;
    const int b = bn >> 9;
    const int n = bn & (NN - 1);
    const int t = threadIdx.x;

    // ---- phase 1: load L rows ----
    {
        float4* Lr4 = (float4*)&Lr[0][0];
        float4* Li4 = (float4*)&Li[0][0];
        for (int i = t; i < KK * (NN/4); i += 128) {
            int k  = i >> 7;        // / 128
            int j4 = i & 127;
            size_t goff = (((size_t)b*KK + k)*NN + n)*NN + (size_t)j4*4;
            Lr4[i] = *(const float4*)(Lr_g + goff);
            Li4[i] = *(const float4*)(Li_g + goff);
        }
    }
    __syncthreads();

    // ---- phase 2: scores + softmax ----
    const float a_r = par[0], a_i = pai[0];
    const float* si_re = ws;
    const float* si_im = ws +     BB*NN*HH;
    const float* sj_re = ws + 2 * BB*NN*HH;
    const float* sj_im = ws + 3 * BB*NN*HH;

    float sir[HH], sii[HH], br[HH], bi[HH];
    #pragma unroll
    for (int h = 0; h < HH; ++h) {
        sir[h] = si_re[bn*HH + h];
        sii[h] = si_im[bn*HH + h];
        br[h]  = abr[h];
        bi[h]  = abi[h];
    }

    float pmax[HH] = {-INFINITY, -INFINITY, -INFINITY, -INFINITY};
    for (int j = t; j < NN; j += 128) {
        float am = fabsf(Lr[0][j]) + fabsf(Lr[1][j]) + fabsf(Lr[2][j]) + fabsf(Lr[3][j]);
        bool msk = am > 1e-9f;
        const float4 sjr4 = *(const float4*)(sj_re + ((size_t)b*NN + j)*HH);
        const float4 sji4 = *(const float4*)(sj_im + ((size_t)b*NN + j)*HH);
        const float* sjrp = (const float*)&sjr4;
        const float* sjip = (const float*)&sji4;
        #pragma unroll
        for (int h = 0; h < HH; ++h) {
            float sr = sir[h] + sjrp[h] + br[h];
            sr = sr >= 0.f ? sr : a_r * sr;
            float sv = sii[h] + sjip[h] + bi[h];
            sv = sv >= 0.f ? sv : a_i * sv;
            float v;
            if (msk) {
                v = sr*sr + sv*sv;
            } else {
                const float NEG = -1e9f;
                v = NEG*NEG + NEG*NEG;   // matches reference exactly
            }
            aw[j][h] = v;
            pmax[h] = fmaxf(pmax[h], v);
        }
    }
    #pragma unroll
    for (int h = 0; h < HH; ++h) red[h][t] = pmax[h];
    __syncthreads();
    if (t < HH) {
        float m = -INFINITY;
        for (int q = 0; q < 128; ++q) m = fmaxf(m, red[t][q]);
        hmax[t] = m;
    }
    __syncthreads();

    float psum[HH] = {0,0,0,0};
    for (int j = t; j < NN; j += 128) {
        #pragma unroll
        for (int h = 0; h < HH; ++h) {
            float e = __expf(aw[j][h] - hmax[h]);
            aw[j][h] = e;
            psum[h] += e;
        }
    }
    #pragma unroll
    for (int h = 0; h < HH; ++h) red[h][t] = psum[h];
    __syncthreads();
    if (t < HH) {
        float s = 0.f;
        for (int q = 0; q < 128; ++q) s += red[t][q];
        hsum[t] = s;
    }
    __syncthreads();

    // ---- phase 3: LX accumulation ----
    const int cp = t & 15;          // c-pair: c = 2*cp, 2*cp+1
    const int h  = (t >> 4) & 3;
    const int jh = t >> 6;          // j-half

    float accR0[KK], accR1[KK], accI0[KK], accI1[KK];
    #pragma unroll
    for (int k = 0; k < KK; ++k) accR0[k]=accR1[k]=accI0[k]=accI1[k]=0.f;

    const size_t xbase = ((size_t)b * NN) * CC + 2*cp;
    const int j0 = jh * (NN/2);
    #pragma unroll 4
    for (int j = j0; j < j0 + NN/2; ++j) {
        float a = aw[j][h];
        float2 xr = *(const float2*)(Xr + xbase + (size_t)j*CC);
        float2 xi = *(const float2*)(Xi + xbase + (size_t)j*CC);
        float axr0 = a*xr.x, axr1 = a*xr.y;
        float axi0 = a*xi.x, axi1 = a*xi.y;
        #pragma unroll
        for (int k = 0; k < KK; ++k) {
            float lr = Lr[k][j], li = Li[k][j];
            accR0[k] = fmaf(lr, axr0, fmaf(-li, axi0, accR0[k]));
            accR1[k] = fmaf(lr, axr1, fmaf(-li, axi1, accR1[k]));
            accI0[k] = fmaf(lr, axi0, fmaf(li, axr0, accI0[k]));
            accI1[k] = fmaf(lr, axi1, fmaf(li, axr1, accI1[k]));
        }
    }

    if (jh == 1) {
        float* p = &part[t - 64][0];
        #pragma unroll
        for (int k = 0; k < KK; ++k) {
            p[k*4+0] = accR0[k]; p[k*4+1] = accR1[k];
            p[k*4+2] = accI0[k]; p[k*4+3] = accI1[k];
        }
    }
    __syncthreads();
    if (jh == 0) {
        const float inv = 1.0f / hsum[h];
        const float* p = &part[t][0];
        #pragma unroll
        for (int k = 0; k < KK; ++k) {
            LXr[k][2*cp+0][h] = (accR0[k] + p[k*4+0]) * inv;
            LXr[k][2*cp+1][h] = (accR1[k] + p[k*4+1]) * inv;
            LXi[k][2*cp+0][h] = (accI0[k] + p[k*4+2]) * inv;
            LXi[k][2*cp+1][h] = (accI1[k] + p[k*4+3]) * inv;
        }
    }
    __syncthreads();

    // ---- phase 4: contract with weights, write out (fp32) ----
    for (int o = t; o < AOUT; o += 128) {
        const int oh = o & 3;
        float yr = 0.f, yi = 0.f;
        #pragma unroll
        for (int k = 0; k < KK; ++k) {
            #pragma unroll 8
            for (int c = 0; c < CC; ++c) {
                float lxr = LXr[k][c][oh];
                float lxi = LXi[k][c][oh];
                float wr = Wr_g[(size_t)(k*CC + c)*AOUT + o];
                float wi = Wi_g[(size_t)(k*CC + c)*AOUT + o];
                yr = fmaf(lxr, wr, fmaf(-lxi, wi, yr));
                yi = fmaf(lxr, wi, fmaf( lxi, wr, yi));
            }
        }
        out[(size_t)bn*AOUT + o] = yr + bsr[o];
        out[(size_t)BB*NN*AOUT + (size_t)bn*AOUT + o] = yi + bsi[o];
    }
}

// ---------------------------------------------------------------------------
extern "C" void kernel_launch(void* const* d_in, const int* in_sizes, int n_in,
                              void* d_out, int out_size, void* d_ws, size_t ws_size,
                              hipStream_t stream)
{
    const float* Xr  = (const float*)d_in[0];
    const float* Xi  = (const float*)d_in[1];
    const float* Lr  = (const float*)d_in[2];
    const float* Li  = (const float*)d_in[3];
    const float* Wr  = (const float*)d_in[4];
    const float* Wi  = (const float*)d_in[5];
    const float* AWr = (const float*)d_in[6];
    const float* AWi = (const float*)d_in[7];
    const float* abr = (const float*)d_in[8];
    const float* abi = (const float*)d_in[9];
    const float* par = (const float*)d_in[10];
    const float* pai = (const float*)d_in[11];
    const float* bsr = (const float*)d_in[12];
    const float* bsi = (const float*)d_in[13];
    float* ws = (float*)d_ws;
    float* out = (float*)d_out;

    hipLaunchKernelGGL(precompute_s_kernel, dim3(8), dim3(256), 0, stream,
                       Xr, Xi, AWr, AWi, ws);
    hipLaunchKernelGGL(cheb_main_kernel, dim3(BB*NN), dim3(128), 0, stream,
                       Xr, Xi, Lr, Li, Wr, Wi, abr, abi, par, pai, bsr, bsi, ws, out);
}

// Round 3
// 52.618 us; speedup vs baseline: 2.4901x; 2.4901x over previous
//
#include <hip/hip_runtime.h>
#include <hip/hip_bf16.h>

#define BB 4
#define NN 512
#define CC 32
#define KK 4      // K+1
#define HH 4
#define AOUT 256

// ws byte offsets
#define WS_SI_F   0              // si_re floats [B*N*H]
#define WS_SII_F  (BB*NN*HH)
#define WS_SJR_F  (2*BB*NN*HH)
#define WS_SJI_F  (3*BB*NN*HH)
#define XT_BASE   131072         // bytes: bf16 X tiles [part][b][jb16][2048B]
#define WR_BASE   393216         // bytes: bf16 Wr [128][256]
#define WI_BASE   458752         // bytes: bf16 Wi [128][256]

typedef __attribute__((ext_vector_type(8))) short bf16x8;
typedef __attribute__((ext_vector_type(4))) float f32x4;

__device__ __forceinline__ ushort f2bfu(float f){
    union { __hip_bfloat16 h; ushort u; } cv;
    cv.h = __float2bfloat16(f);
    return cv.u;
}
__device__ __forceinline__ short f2bfs(float f){ return (short)f2bfu(f); }
__device__ __forceinline__ float bfu2f(unsigned int u){ return __uint_as_float(u << 16); }

// ---------------------------------------------------------------------------
// Kernel A: per (b,n) attention projections si/sj (re/im)
// ---------------------------------------------------------------------------
__global__ __launch_bounds__(256) void precompute_s_kernel(
    const float* __restrict__ Xr, const float* __restrict__ Xi,
    const float* __restrict__ AWr, const float* __restrict__ AWi,
    float* __restrict__ ws)
{
    int idx = blockIdx.x * blockDim.x + threadIdx.x;
    if (idx >= BB * NN) return;
    const float* xr = Xr + (size_t)idx * CC;
    const float* xi = Xi + (size_t)idx * CC;
    float sir[HH] = {0,0,0,0}, sii[HH] = {0,0,0,0};
    float sjr[HH] = {0,0,0,0}, sji[HH] = {0,0,0,0};
    for (int c = 0; c < CC; ++c) {
        float xrc = xr[c], xic = xi[c];
        const float* w1r = AWr + c*HH;
        const float* w1i = AWi + c*HH;
        const float* w2r = AWr + (CC + c)*HH;
        const float* w2i = AWi + (CC + c)*HH;
        #pragma unroll
        for (int h = 0; h < HH; ++h) {
            sir[h] = fmaf(xrc, w1r[h], fmaf(-xic, w1i[h], sir[h]));
            sii[h] = fmaf(xrc, w1i[h], fmaf( xic, w1r[h], sii[h]));
            sjr[h] = fmaf(xrc, w2r[h], fmaf(-xic, w2i[h], sjr[h]));
            sji[h] = fmaf(xrc, w2i[h], fmaf( xic, w2r[h], sji[h]));
        }
    }
    #pragma unroll
    for (int h = 0; h < HH; ++h) {
        ws[WS_SI_F  + idx*HH + h] = sir[h];
        ws[WS_SII_F + idx*HH + h] = sii[h];
        ws[WS_SJR_F + idx*HH + h] = sjr[h];
        ws[WS_SJI_F + idx*HH + h] = sji[h];
    }
}

// ---------------------------------------------------------------------------
// Kernel B: pack X -> bf16 tiles. Tile = 32 j x 32 c, 1KB, laid out so a
// B-fragment (c = l&15 (+16*ct), j = jg*8+e) is one coalesced dwordx4.
// byte in tile = c*64 + (j&31)*2
// ---------------------------------------------------------------------------
__global__ __launch_bounds__(64) void pack_xt_kernel(
    const float* __restrict__ Xr, const float* __restrict__ Xi,
    char* __restrict__ wsB)
{
    int bid = blockIdx.x;           // part*64 + b*16 + jb
    int part = bid >> 6, b = (bid >> 4) & 3, jb = bid & 15;
    const float* X = part ? Xi : Xr;
    int lane = threadIdx.x;
    int c = lane & 31, jh = lane >> 5;   // jh: which 16-j half

    unsigned int w[8];
    #pragma unroll
    for (int q = 0; q < 8; ++q) {
        int ji = jh*16 + q*2;
        float f0 = X[((size_t)b*NN + jb*32 + ji  )*CC + c];
        float f1 = X[((size_t)b*NN + jb*32 + ji+1)*CC + c];
        w[q] = (unsigned int)f2bfu(f0) | ((unsigned int)f2bfu(f1) << 16);
    }
    char* tile = wsB + XT_BASE + (((size_t)(part*4 + b)*16 + jb) * 2048);
    uint4* dst = (uint4*)(tile + c*64 + jh*32);
    dst[0] = make_uint4(w[0], w[1], w[2], w[3]);
    dst[1] = make_uint4(w[4], w[5], w[6], w[7]);
}

// ---------------------------------------------------------------------------
// Kernel C: pack weights -> bf16 (halves phase-4 L2 traffic)
// ---------------------------------------------------------------------------
__global__ __launch_bounds__(256) void pack_w_kernel(
    const float* __restrict__ Wr, const float* __restrict__ Wi,
    char* __restrict__ wsB)
{
    int idx = blockIdx.x * 256 + threadIdx.x;   // 0..32767
    ((ushort*)(wsB + WR_BASE))[idx] = f2bfu(Wr[idx]);
    ((ushort*)(wsB + WI_BASE))[idx] = f2bfu(Wi[idx]);
}

// ---------------------------------------------------------------------------
// Kernel D: main. One block per (b,n), 128 threads (2 waves).
//  P1: stage L (fp32, stride 516 -> conflict-free b128 reads)
//  P2: scores+softmax, aw[h][516] unnormalized exps, shuffle reductions
//  P3: MFMA GEMM [Mr;Mi](16x512) @ [Xr|Xi](512x32), K split across 2 waves
//  P4: weight contraction with bf16 W
// ---------------------------------------------------------------------------
__global__ __launch_bounds__(128) void cheb_main_kernel(
    const float* __restrict__ Lr_g, const float* __restrict__ Li_g,
    const float* __restrict__ abr, const float* __restrict__ abi,
    const float* __restrict__ par, const float* __restrict__ pai,
    const float* __restrict__ bsr, const float* __restrict__ bsi,
    const float* __restrict__ ws, char* __restrict__ wsB,
    float* __restrict__ out)
{
    __shared__ float Lf[8][516];        // (p*4+k) rows; 16512 B
    __shared__ float awf[HH][516];      // exp values; 8256 B (reused as reduce buf)
    __shared__ float LXr[KK][CC][6];    // 3072 B (pad 6: conflict-light, float2-able)
    __shared__ float LXi[KK][CC][6];    // 3072 B
    __shared__ float wredm[2][HH];
    __shared__ float wreds[2][HH];

    const int bn = blockIdx.x;
    const int b = bn >> 9;
    const int n = bn & (NN - 1);
    const int t = threadIdx.x;
    const int l = t & 63;
    const int w = t >> 6;

    // ---- P1: stage L ----
    #pragma unroll
    for (int it = 0; it < 8; ++it) {
        int i = t + it*128;             // 0..1023 float4 chunks
        int pk = i >> 7;                // wave-uniform per iteration
        int j4 = i & 127;
        int k = pk & 3;
        const float* src = (pk & 4) ? Li_g : Lr_g;
        size_t goff = (((size_t)b*KK + k)*NN + n)*NN + (size_t)j4*4;
        *(float4*)&Lf[pk][j4*4] = *(const float4*)(src + goff);
    }
    __syncthreads();

    // ---- P2: scores + softmax ----
    const float a_r = par[0], a_i = pai[0];
    float sir[HH], sii[HH];
    #pragma unroll
    for (int h = 0; h < HH; ++h) {
        sir[h] = ws[WS_SI_F  + bn*HH + h] + abr[h];
        sii[h] = ws[WS_SII_F + bn*HH + h] + abi[h];
    }

    float pmax[HH] = {-INFINITY, -INFINITY, -INFINITY, -INFINITY};
    #pragma unroll
    for (int jj = 0; jj < 4; ++jj) {
        int j = t + jj*128;
        float am = fabsf(Lf[0][j]) + fabsf(Lf[1][j]) + fabsf(Lf[2][j]) + fabsf(Lf[3][j]);
        bool msk = am > 1e-9f;
        const float4 sjr4 = *(const float4*)(ws + WS_SJR_F + ((size_t)b*NN + j)*HH);
        const float4 sji4 = *(const float4*)(ws + WS_SJI_F + ((size_t)b*NN + j)*HH);
        const float* sjrp = (const float*)&sjr4;
        const float* sjip = (const float*)&sji4;
        #pragma unroll
        for (int h = 0; h < HH; ++h) {
            float sr = sir[h] + sjrp[h];
            sr = sr >= 0.f ? sr : a_r * sr;
            float sv = sii[h] + sjip[h];
            sv = sv >= 0.f ? sv : a_i * sv;
            float v;
            if (msk) v = sr*sr + sv*sv;
            else { const float NEG = -1e9f; v = NEG*NEG + NEG*NEG; }
            awf[h][j] = v;
            pmax[h] = fmaxf(pmax[h], v);
        }
    }
    #pragma unroll
    for (int h = 0; h < HH; ++h) {
        #pragma unroll
        for (int off = 32; off > 0; off >>= 1)
            pmax[h] = fmaxf(pmax[h], __shfl_xor(pmax[h], off));
    }
    if (l == 0) { wredm[w][0]=pmax[0]; wredm[w][1]=pmax[1]; wredm[w][2]=pmax[2]; wredm[w][3]=pmax[3]; }
    __syncthreads();
    float hm[HH];
    #pragma unroll
    for (int h = 0; h < HH; ++h) hm[h] = fmaxf(wredm[0][h], wredm[1][h]);

    float psum[HH] = {0,0,0,0};
    #pragma unroll
    for (int jj = 0; jj < 4; ++jj) {
        int j = t + jj*128;
        #pragma unroll
        for (int h = 0; h < HH; ++h) {
            float e = __expf(awf[h][j] - hm[h]);
            awf[h][j] = e;
            psum[h] += e;
        }
    }
    #pragma unroll
    for (int h = 0; h < HH; ++h) {
        #pragma unroll
        for (int off = 32; off > 0; off >>= 1)
            psum[h] += __shfl_xor(psum[h], off);
    }
    if (l == 0) { wreds[w][0]=psum[0]; wreds[w][1]=psum[1]; wreds[w][2]=psum[2]; wreds[w][3]=psum[3]; }
    __syncthreads();          // also makes all awf exp-writes visible
    float inv[HH];
    #pragma unroll
    for (int h = 0; h < HH; ++h) inv[h] = 1.0f / (wreds[0][h] + wreds[1][h]);

    // ---- P3: MFMA GEMM. wave w owns j in [w*256, w*256+256) ----
    const int r_a = l & 15;             // A row = k*4+h
    const int jg  = l >> 4;             // j-group (8 j's each)
    const int k_a = r_a >> 2, h_a = r_a & 3;

    f32x4 acc[8];                        // RR0 RR1 II0 II1 RI0 RI1 IR0 IR1
    #pragma unroll
    for (int a = 0; a < 8; ++a) acc[a] = (f32x4){0.f,0.f,0.f,0.f};

    const char* xtR = wsB + XT_BASE + ((size_t)(0*4 + b)*16 + w*8)*2048;
    const char* xtI = wsB + XT_BASE + ((size_t)(4 + b)*16 + w*8)*2048;
    const int bofs = (l & 15)*64 + jg*16;

    #pragma unroll 2
    for (int s = 0; s < 8; ++s) {
        const int j0 = w*256 + s*32 + jg*8;
        float4 lrA = *(const float4*)&Lf[k_a][j0];
        float4 lrB = *(const float4*)&Lf[k_a][j0+4];
        float4 liA = *(const float4*)&Lf[4+k_a][j0];
        float4 liB = *(const float4*)&Lf[4+k_a][j0+4];
        float4 awA = *(const float4*)&awf[h_a][j0];
        float4 awB = *(const float4*)&awf[h_a][j0+4];

        bf16x8 Ar, Ai;
        Ar[0]=f2bfs(lrA.x*awA.x); Ar[1]=f2bfs(lrA.y*awA.y);
        Ar[2]=f2bfs(lrA.z*awA.z); Ar[3]=f2bfs(lrA.w*awA.w);
        Ar[4]=f2bfs(lrB.x*awB.x); Ar[5]=f2bfs(lrB.y*awB.y);
        Ar[6]=f2bfs(lrB.z*awB.z); Ar[7]=f2bfs(lrB.w*awB.w);
        Ai[0]=f2bfs(liA.x*awA.x); Ai[1]=f2bfs(liA.y*awA.y);
        Ai[2]=f2bfs(liA.z*awA.z); Ai[3]=f2bfs(liA.w*awA.w);
        Ai[4]=f2bfs(liB.x*awB.x); Ai[5]=f2bfs(liB.y*awB.y);
        Ai[6]=f2bfs(liB.z*awB.z); Ai[7]=f2bfs(liB.w*awB.w);

        bf16x8 Br0 = *(const bf16x8*)(xtR + s*2048 +        bofs);
        bf16x8 Br1 = *(const bf16x8*)(xtR + s*2048 + 1024 + bofs);
        bf16x8 Bi0 = *(const bf16x8*)(xtI + s*2048 +        bofs);
        bf16x8 Bi1 = *(const bf16x8*)(xtI + s*2048 + 1024 + bofs);

        acc[0] = __builtin_amdgcn_mfma_f32_16x16x32_bf16(Ar, Br0, acc[0], 0, 0, 0);
        acc[1] = __builtin_amdgcn_mfma_f32_16x16x32_bf16(Ar, Br1, acc[1], 0, 0, 0);
        acc[2] = __builtin_amdgcn_mfma_f32_16x16x32_bf16(Ai, Bi0, acc[2], 0, 0, 0);
        acc[3] = __builtin_amdgcn_mfma_f32_16x16x32_bf16(Ai, Bi1, acc[3], 0, 0, 0);
        acc[4] = __builtin_amdgcn_mfma_f32_16x16x32_bf16(Ar, Bi0, acc[4], 0, 0, 0);
        acc[5] = __builtin_amdgcn_mfma_f32_16x16x32_bf16(Ar, Bi1, acc[5], 0, 0, 0);
        acc[6] = __builtin_amdgcn_mfma_f32_16x16x32_bf16(Ai, Br0, acc[6], 0, 0, 0);
        acc[7] = __builtin_amdgcn_mfma_f32_16x16x32_bf16(Ai, Br1, acc[7], 0, 0, 0);
    }
    __syncthreads();                     // aw/Lf reads done; awf reusable

    float* pbuf = &awf[0][0];
    if (w == 1) {
        #pragma unroll
        for (int a = 0; a < 8; ++a)
            #pragma unroll
            for (int r = 0; r < 4; ++r)
                pbuf[(a*4 + r)*64 + l] = acc[a][r];
    }
    __syncthreads();
    if (w == 0) {
        const int kk = l >> 4, lc = l & 15;
        #pragma unroll
        for (int a = 0; a < 8; ++a)
            #pragma unroll
            for (int r = 0; r < 4; ++r)
                acc[a][r] += pbuf[(a*4 + r)*64 + l];
        #pragma unroll
        for (int ct = 0; ct < 2; ++ct) {
            #pragma unroll
            for (int r = 0; r < 4; ++r) {
                float iv = inv[r];      // h == reg index (D row = (l>>4)*4+r)
                LXr[kk][ct*16+lc][r] = (acc[0+ct][r] - acc[2+ct][r]) * iv;
                LXi[kk][ct*16+lc][r] = (acc[4+ct][r] + acc[6+ct][r]) * iv;
            }
        }
    }
    __syncthreads();

    // ---- P4: weight contraction (bf16 W), thread owns o=2t, 2t+1 ----
    const ushort* wrp = (const ushort*)(wsB + WR_BASE);
    const ushort* wip = (const ushort*)(wsB + WI_BASE);
    const int o0 = 2*t, o1 = 2*t + 1;
    const int oh0 = o0 & 3;
    float yr0=0.f, yi0=0.f, yr1=0.f, yi1=0.f;
    #pragma unroll 8
    for (int kc = 0; kc < 128; ++kc) {
        int k = kc >> 5, c = kc & 31;
        float lxr0 = LXr[k][c][oh0], lxr1 = LXr[k][c][oh0+1];
        float lxi0 = LXi[k][c][oh0], lxi1 = LXi[k][c][oh0+1];
        unsigned int wr2 = *(const unsigned int*)(wrp + kc*AOUT + o0);
        unsigned int wi2 = *(const unsigned int*)(wip + kc*AOUT + o0);
        float wr0 = bfu2f(wr2 & 0xffffu), wr1 = bfu2f(wr2 >> 16);
        float wi0 = bfu2f(wi2 & 0xffffu), wi1 = bfu2f(wi2 >> 16);
        yr0 = fmaf(lxr0, wr0, fmaf(-lxi0, wi0, yr0));
        yi0 = fmaf(lxr0, wi0, fmaf( lxi0, wr0, yi0));
        yr1 = fmaf(lxr1, wr1, fmaf(-lxi1, wi1, yr1));
        yi1 = fmaf(lxr1, wi1, fmaf( lxi1, wr1, yi1));
    }
    out[(size_t)bn*AOUT + o0] = yr0 + bsr[o0];
    out[(size_t)bn*AOUT + o1] = yr1 + bsr[o1];
    out[(size_t)BB*NN*AOUT + (size_t)bn*AOUT + o0] = yi0 + bsi[o0];
    out[(size_t)BB*NN*AOUT + (size_t)bn*AOUT + o1] = yi1 + bsi[o1];
}

// ---------------------------------------------------------------------------
extern "C" void kernel_launch(void* const* d_in, const int* in_sizes, int n_in,
                              void* d_out, int out_size, void* d_ws, size_t ws_size,
                              hipStream_t stream)
{
    const float* Xr  = (const float*)d_in[0];
    const float* Xi  = (const float*)d_in[1];
    const float* Lr  = (const float*)d_in[2];
    const float* Li  = (const float*)d_in[3];
    const float* Wr  = (const float*)d_in[4];
    const float* Wi  = (const float*)d_in[5];
    const float* AWr = (const float*)d_in[6];
    const float* AWi = (const float*)d_in[7];
    const float* abr = (const float*)d_in[8];
    const float* abi = (const float*)d_in[9];
    const float* par = (const float*)d_in[10];
    const float* pai = (const float*)d_in[11];
    const float* bsr = (const float*)d_in[12];
    const float* bsi = (const float*)d_in[13];
    float* ws  = (float*)d_ws;
    char*  wsB = (char*)d_ws;
    float* out = (float*)d_out;

    hipLaunchKernelGGL(precompute_s_kernel, dim3(8), dim3(256), 0, stream,
                       Xr, Xi, AWr, AWi, ws);
    hipLaunchKernelGGL(pack_xt_kernel, dim3(128), dim3(64), 0, stream,
                       Xr, Xi, wsB);
    hipLaunchKernelGGL(pack_w_kernel, dim3(128), dim3(256), 0, stream,
                       Wr, Wi, wsB);
    hipLaunchKernelGGL(cheb_main_kernel, dim3(BB*NN), dim3(128), 0, stream,
                       Lr, Li, abr, abi, par, pai, bsr, bsi, ws, wsB, out);
}

// Round 4
// 36.057 us; speedup vs baseline: 3.6337x; 1.4593x over previous
//
#include <hip/hip_runtime.h>
#include <hip/hip_bf16.h>

#define BB 4
#define NN 512
#define CC 32
#define KK 4      // K+1
#define HH 4
#define AOUT 256

// ws float-index offsets (si/sj)
#define WS_SI_F   0
#define WS_SII_F  (BB*NN*HH)
#define WS_SJR_F  (2*BB*NN*HH)
#define WS_SJI_F  (3*BB*NN*HH)
// ws byte offsets
#define XT_BASE   131072         // bf16 X tiles [part][b][jb16] x 2048 B
#define LX_BASE   393216         // bf16 LX [bn] x 2048 B   (4 MB)
#define BRE_BASE  4587520        // bf16 B_re fragments, 128 KB
#define BIM_BASE  4718592        // bf16 B_im fragments, 128 KB

typedef __attribute__((ext_vector_type(8))) short bf16x8;
typedef __attribute__((ext_vector_type(4))) float f32x4;

__device__ __forceinline__ ushort f2bfu(float f){
    union { __hip_bfloat16 h; ushort u; } cv;
    cv.h = __float2bfloat16(f);
    return cv.u;
}
__device__ __forceinline__ short f2bfs(float f){ return (short)f2bfu(f); }
__device__ __forceinline__ float bfu2f(unsigned int u){ return __uint_as_float(u << 16); }

// ---------------------------------------------------------------------------
// Fused prep kernel: grid 72 x 256
//  blk 0..7   : si/sj attention projections (2048 threads)
//  blk 8..39  : pack X -> bf16 tiles (tile 32j x 32c = 2 KB; byte = c*64+(j&31)*2)
//  blk 40..71 : pack W -> B-fragment layout for out GEMM
// ---------------------------------------------------------------------------
__global__ __launch_bounds__(256) void prep_kernel(
    const float* __restrict__ Xr, const float* __restrict__ Xi,
    const float* __restrict__ AWr, const float* __restrict__ AWi,
    const float* __restrict__ Wr, const float* __restrict__ Wi,
    float* __restrict__ ws, char* __restrict__ wsB)
{
    const int blk = blockIdx.x;
    const int t = threadIdx.x;

    if (blk < 8) {
        int idx = blk*256 + t;
        const float* xr = Xr + (size_t)idx * CC;
        const float* xi = Xi + (size_t)idx * CC;
        float sir[HH] = {0,0,0,0}, sii[HH] = {0,0,0,0};
        float sjr[HH] = {0,0,0,0}, sji[HH] = {0,0,0,0};
        for (int c = 0; c < CC; ++c) {
            float xrc = xr[c], xic = xi[c];
            const float* w1r = AWr + c*HH;
            const float* w1i = AWi + c*HH;
            const float* w2r = AWr + (CC + c)*HH;
            const float* w2i = AWi + (CC + c)*HH;
            #pragma unroll
            for (int h = 0; h < HH; ++h) {
                sir[h] = fmaf(xrc, w1r[h], fmaf(-xic, w1i[h], sir[h]));
                sii[h] = fmaf(xrc, w1i[h], fmaf( xic, w1r[h], sii[h]));
                sjr[h] = fmaf(xrc, w2r[h], fmaf(-xic, w2i[h], sjr[h]));
                sji[h] = fmaf(xrc, w2i[h], fmaf( xic, w2r[h], sji[h]));
            }
        }
        #pragma unroll
        for (int h = 0; h < HH; ++h) {
            ws[WS_SI_F  + idx*HH + h] = sir[h];
            ws[WS_SII_F + idx*HH + h] = sii[h];
            ws[WS_SJR_F + idx*HH + h] = sjr[h];
            ws[WS_SJI_F + idx*HH + h] = sji[h];
        }
    } else if (blk < 40) {
        int bid = (blk - 8)*4 + (t >> 6);    // 0..127: part*64 + b*16 + jb
        int part = bid >> 6, b = (bid >> 4) & 3, jb = bid & 15;
        const float* X = part ? Xi : Xr;
        int lane = t & 63;
        int c = lane & 31, jh = lane >> 5;

        unsigned int w[8];
        #pragma unroll
        for (int q = 0; q < 8; ++q) {
            int ji = jh*16 + q*2;
            float f0 = X[((size_t)b*NN + jb*32 + ji  )*CC + c];
            float f1 = X[((size_t)b*NN + jb*32 + ji+1)*CC + c];
            w[q] = (unsigned int)f2bfu(f0) | ((unsigned int)f2bfu(f1) << 16);
        }
        char* tile = wsB + XT_BASE + (((size_t)(part*4 + b)*16 + jb) * 2048);
        uint4* dst = (uint4*)(tile + c*64 + jh*32);
        dst[0] = make_uint4(w[0], w[1], w[2], w[3]);
        dst[1] = make_uint4(w[4], w[5], w[6], w[7]);
    } else {
        // W fragment pack: idx over [h][Nt][s][lane]
        int idx = (blk - 40)*256 + t;        // 0..8191
        int l  = idx & 63;
        int s  = (idx >> 6) & 7;
        int Nt = (idx >> 9) & 3;
        int h  = idx >> 11;
        int p = Nt*16 + (l & 15), o = p*4 + h;
        int e8 = (l >> 4) * 8;
        unsigned int re_w[4], im_w[4];
        #pragma unroll
        for (int q = 0; q < 4; ++q) {
            unsigned int rw = 0, iw = 0;
            #pragma unroll
            for (int half = 0; half < 2; ++half) {
                int kpos = s*32 + e8 + q*2 + half;
                int ri = kpos >> 7, kk = (kpos >> 5) & 3, c = kpos & 31;
                float wr = Wr[(size_t)(kk*CC + c)*AOUT + o];
                float wi = Wi[(size_t)(kk*CC + c)*AOUT + o];
                unsigned int vre = f2bfu(ri ? -wi : wr);
                unsigned int vim = f2bfu(ri ?  wr : wi);
                rw |= vre << (16*half);
                iw |= vim << (16*half);
            }
            re_w[q] = rw; im_w[q] = iw;
        }
        size_t fo = ((size_t)((h*4 + Nt)*8 + s))*1024 + (size_t)l*16;
        *(uint4*)(wsB + BRE_BASE + fo) = make_uint4(re_w[0], re_w[1], re_w[2], re_w[3]);
        *(uint4*)(wsB + BIM_BASE + fo) = make_uint4(im_w[0], im_w[1], im_w[2], im_w[3]);
    }
}

// ---------------------------------------------------------------------------
// Main kernel: one block per (b,n), 128 threads (2 waves). LDS ~16.8 KB.
//  P1: stage L -> bf16 LDS (row stride 528 -> max 2-way bank alias on b128 reads)
//  P2: scores + softmax (mask from bf16 L; unnormalized exps in awf fp32)
//  P3: MFMA [Mr;Mi](16x512) @ [Xr|Xi](512x32); j split across 2 waves
//  end: cross-wave reduce (pbuf = awf reuse), write normalized LX bf16 to ws
// ---------------------------------------------------------------------------
__global__ __launch_bounds__(128) void cheb_main_kernel(
    const float* __restrict__ Lr_g, const float* __restrict__ Li_g,
    const float* __restrict__ abr, const float* __restrict__ abi,
    const float* __restrict__ par, const float* __restrict__ pai,
    const float* __restrict__ ws, char* __restrict__ wsB)
{
    __shared__ ushort Lf[8][528];      // bf16 bits; 8448 B
    __shared__ float awf[HH][516];     // 8256 B; reused as pbuf (needs 8192)
    __shared__ float wredm[2][HH];
    __shared__ float wreds[2][HH];

    const int bn = blockIdx.x;
    const int b = bn >> 9;
    const int n = bn & (NN - 1);
    const int t = threadIdx.x;
    const int l = t & 63;
    const int w = t >> 6;

    // ---- P1: stage L as bf16 ----
    #pragma unroll
    for (int it = 0; it < 8; ++it) {
        int k = it & 3;
        const float* src = (it & 4) ? Li_g : Lr_g;
        size_t goff = (((size_t)b*KK + k)*NN + n)*NN + (size_t)t*4;
        float4 v = *(const float4*)(src + goff);
        ushort4 u;
        u.x = f2bfu(v.x); u.y = f2bfu(v.y); u.z = f2bfu(v.z); u.w = f2bfu(v.w);
        *(ushort4*)&Lf[it][t*4] = u;
    }
    __syncthreads();

    // ---- P2: scores + softmax ----
    const float a_r = par[0], a_i = pai[0];
    float sir[HH], sii[HH];
    #pragma unroll
    for (int h = 0; h < HH; ++h) {
        sir[h] = ws[WS_SI_F  + bn*HH + h] + abr[h];
        sii[h] = ws[WS_SII_F + bn*HH + h] + abi[h];
    }

    float pmax[HH] = {-INFINITY, -INFINITY, -INFINITY, -INFINITY};
    #pragma unroll
    for (int jj = 0; jj < 4; ++jj) {
        int j = t + jj*128;
        float am = fabsf(bfu2f(Lf[0][j])) + fabsf(bfu2f(Lf[1][j]))
                 + fabsf(bfu2f(Lf[2][j])) + fabsf(bfu2f(Lf[3][j]));
        bool msk = am > 1e-9f;
        const float4 sjr4 = *(const float4*)(ws + WS_SJR_F + ((size_t)b*NN + j)*HH);
        const float4 sji4 = *(const float4*)(ws + WS_SJI_F + ((size_t)b*NN + j)*HH);
        const float* sjrp = (const float*)&sjr4;
        const float* sjip = (const float*)&sji4;
        #pragma unroll
        for (int h = 0; h < HH; ++h) {
            float sr = sir[h] + sjrp[h];
            sr = sr >= 0.f ? sr : a_r * sr;
            float sv = sii[h] + sjip[h];
            sv = sv >= 0.f ? sv : a_i * sv;
            float v;
            if (msk) v = sr*sr + sv*sv;
            else { const float NEG = -1e9f; v = NEG*NEG + NEG*NEG; }
            awf[h][j] = v;
            pmax[h] = fmaxf(pmax[h], v);
        }
    }
    #pragma unroll
    for (int h = 0; h < HH; ++h) {
        #pragma unroll
        for (int off = 32; off > 0; off >>= 1)
            pmax[h] = fmaxf(pmax[h], __shfl_xor(pmax[h], off));
    }
    if (l == 0) { wredm[w][0]=pmax[0]; wredm[w][1]=pmax[1]; wredm[w][2]=pmax[2]; wredm[w][3]=pmax[3]; }
    __syncthreads();
    float hm[HH];
    #pragma unroll
    for (int h = 0; h < HH; ++h) hm[h] = fmaxf(wredm[0][h], wredm[1][h]);

    float psum[HH] = {0,0,0,0};
    #pragma unroll
    for (int jj = 0; jj < 4; ++jj) {
        int j = t + jj*128;
        #pragma unroll
        for (int h = 0; h < HH; ++h) {
            float e = __expf(awf[h][j] - hm[h]);
            awf[h][j] = e;
            psum[h] += e;
        }
    }
    #pragma unroll
    for (int h = 0; h < HH; ++h) {
        #pragma unroll
        for (int off = 32; off > 0; off >>= 1)
            psum[h] += __shfl_xor(psum[h], off);
    }
    if (l == 0) { wreds[w][0]=psum[0]; wreds[w][1]=psum[1]; wreds[w][2]=psum[2]; wreds[w][3]=psum[3]; }
    __syncthreads();      // exps visible; sums ready
    float inv[HH];
    #pragma unroll
    for (int h = 0; h < HH; ++h) inv[h] = 1.0f / (wreds[0][h] + wreds[1][h]);

    // ---- P3: MFMA. wave w owns j in [w*256, w*256+256) ----
    const int r_a = l & 15;              // A row = k*4+h
    const int jg  = l >> 4;
    const int k_a = r_a >> 2, h_a = r_a & 3;

    f32x4 acc[8];                        // RR0 RR1 II0 II1 RI0 RI1 IR0 IR1
    #pragma unroll
    for (int a = 0; a < 8; ++a) acc[a] = (f32x4){0.f,0.f,0.f,0.f};

    const char* xtR = wsB + XT_BASE + ((size_t)(0*4 + b)*16 + w*8)*2048;
    const char* xtI = wsB + XT_BASE + ((size_t)(4   + b)*16 + w*8)*2048;
    const int bofs = (l & 15)*64 + jg*16;

    #pragma unroll 2
    for (int s = 0; s < 8; ++s) {
        const int j0 = w*256 + s*32 + jg*8;
        bf16x8 lr8 = *(const bf16x8*)&Lf[k_a][j0];
        bf16x8 li8 = *(const bf16x8*)&Lf[4 + k_a][j0];
        float aww[8];
        *(float4*)&aww[0] = *(const float4*)&awf[h_a][j0];
        *(float4*)&aww[4] = *(const float4*)&awf[h_a][j0 + 4];

        bf16x8 Ar, Ai;
        #pragma unroll
        for (int e = 0; e < 8; ++e) {
            float lrv = bfu2f((ushort)lr8[e]);
            float liv = bfu2f((ushort)li8[e]);
            Ar[e] = f2bfs(lrv * aww[e]);
            Ai[e] = f2bfs(liv * aww[e]);
        }

        bf16x8 Br0 = *(const bf16x8*)(xtR + s*2048 +        bofs);
        bf16x8 Br1 = *(const bf16x8*)(xtR + s*2048 + 1024 + bofs);
        bf16x8 Bi0 = *(const bf16x8*)(xtI + s*2048 +        bofs);
        bf16x8 Bi1 = *(const bf16x8*)(xtI + s*2048 + 1024 + bofs);

        acc[0] = __builtin_amdgcn_mfma_f32_16x16x32_bf16(Ar, Br0, acc[0], 0, 0, 0);
        acc[1] = __builtin_amdgcn_mfma_f32_16x16x32_bf16(Ar, Br1, acc[1], 0, 0, 0);
        acc[2] = __builtin_amdgcn_mfma_f32_16x16x32_bf16(Ai, Bi0, acc[2], 0, 0, 0);
        acc[3] = __builtin_amdgcn_mfma_f32_16x16x32_bf16(Ai, Bi1, acc[3], 0, 0, 0);
        acc[4] = __builtin_amdgcn_mfma_f32_16x16x32_bf16(Ar, Bi0, acc[4], 0, 0, 0);
        acc[5] = __builtin_amdgcn_mfma_f32_16x16x32_bf16(Ar, Bi1, acc[5], 0, 0, 0);
        acc[6] = __builtin_amdgcn_mfma_f32_16x16x32_bf16(Ai, Br0, acc[6], 0, 0, 0);
        acc[7] = __builtin_amdgcn_mfma_f32_16x16x32_bf16(Ai, Br1, acc[7], 0, 0, 0);
    }
    __syncthreads();                     // all awf/Lf reads done

    float* pbuf = &awf[0][0];
    if (w == 1) {
        #pragma unroll
        for (int a = 0; a < 8; ++a)
            #pragma unroll
            for (int r = 0; r < 4; ++r)
                pbuf[(a*4 + r)*64 + l] = acc[a][r];
    }
    __syncthreads();
    if (w == 0) {
        const int kk = l >> 4, lc = l & 15;
        #pragma unroll
        for (int a = 0; a < 8; ++a)
            #pragma unroll
            for (int r = 0; r < 4; ++r)
                acc[a][r] += pbuf[(a*4 + r)*64 + l];
        // write LX bf16: [bn](2048B) layout [h][ri][k][c]
        char* lxp = wsB + LX_BASE + (size_t)bn*2048;
        #pragma unroll
        for (int ct = 0; ct < 2; ++ct) {
            const int c = ct*16 + lc;
            #pragma unroll
            for (int r = 0; r < 4; ++r) {   // r == h
                float iv = inv[r];
                float vr = (acc[0+ct][r] - acc[2+ct][r]) * iv;
                float vi = (acc[4+ct][r] + acc[6+ct][r]) * iv;
                *(ushort*)(lxp + r*512 +       kk*64 + c*2) = f2bfu(vr);
                *(ushort*)(lxp + r*512 + 256 + kk*64 + c*2) = f2bfu(vi);
            }
        }
    }
}

// ---------------------------------------------------------------------------
// Out GEMM: Y[bn,o] = [LXr|LXi] @ Bre/Bim (K=256), + bias.
// grid 128 blocks x 256 thr; wave = (Mtile=blockIdx, h=wave_id); 4 N-tiles/wave.
// ---------------------------------------------------------------------------
__global__ __launch_bounds__(256) void out_gemm_kernel(
    const char* __restrict__ wsB,
    const float* __restrict__ bsr, const float* __restrict__ bsi,
    float* __restrict__ out)
{
    const int Mtile = blockIdx.x;
    const int t = threadIdx.x, l = t & 63, h = t >> 6;

    const char* abase = wsB + LX_BASE + ((size_t)(Mtile*16 + (l & 15)))*2048
                        + h*512 + (l >> 4)*16;
    bf16x8 Af[8];
    #pragma unroll
    for (int s = 0; s < 8; ++s) Af[s] = *(const bf16x8*)(abase + s*64);

    #pragma unroll
    for (int Nt = 0; Nt < 4; ++Nt) {
        f32x4 are = (f32x4){0.f,0.f,0.f,0.f};
        f32x4 aim = (f32x4){0.f,0.f,0.f,0.f};
        const size_t fbase = ((size_t)((h*4 + Nt)*8))*1024 + (size_t)l*16;
        const char* bre = wsB + BRE_BASE + fbase;
        const char* bim = wsB + BIM_BASE + fbase;
        #pragma unroll
        for (int s = 0; s < 8; ++s) {
            bf16x8 Br = *(const bf16x8*)(bre + s*1024);
            bf16x8 Bi = *(const bf16x8*)(bim + s*1024);
            are = __builtin_amdgcn_mfma_f32_16x16x32_bf16(Af[s], Br, are, 0, 0, 0);
            aim = __builtin_amdgcn_mfma_f32_16x16x32_bf16(Af[s], Bi, aim, 0, 0, 0);
        }
        const int p = Nt*16 + (l & 15), o = p*4 + h;
        const float vbr = bsr[o], vbi = bsi[o];
        #pragma unroll
        for (int r = 0; r < 4; ++r) {
            int bn = Mtile*16 + (l >> 4)*4 + r;
            out[(size_t)bn*AOUT + o] = are[r] + vbr;
            out[(size_t)BB*NN*AOUT + (size_t)bn*AOUT + o] = aim[r] + vbi;
        }
    }
}

// ---------------------------------------------------------------------------
extern "C" void kernel_launch(void* const* d_in, const int* in_sizes, int n_in,
                              void* d_out, int out_size, void* d_ws, size_t ws_size,
                              hipStream_t stream)
{
    const float* Xr  = (const float*)d_in[0];
    const float* Xi  = (const float*)d_in[1];
    const float* Lr  = (const float*)d_in[2];
    const float* Li  = (const float*)d_in[3];
    const float* Wr  = (const float*)d_in[4];
    const float* Wi  = (const float*)d_in[5];
    const float* AWr = (const float*)d_in[6];
    const float* AWi = (const float*)d_in[7];
    const float* abr = (const float*)d_in[8];
    const float* abi = (const float*)d_in[9];
    const float* par = (const float*)d_in[10];
    const float* pai = (const float*)d_in[11];
    const float* bsr = (const float*)d_in[12];
    const float* bsi = (const float*)d_in[13];
    float* ws  = (float*)d_ws;
    char*  wsB = (char*)d_ws;
    float* out = (float*)d_out;

    hipLaunchKernelGGL(prep_kernel, dim3(72), dim3(256), 0, stream,
                       Xr, Xi, AWr, AWi, Wr, Wi, ws, wsB);
    hipLaunchKernelGGL(cheb_main_kernel, dim3(BB*NN), dim3(128), 0, stream,
                       Lr, Li, abr, abi, par, pai, ws, wsB);
    hipLaunchKernelGGL(out_gemm_kernel, dim3(128), dim3(256), 0, stream,
                       wsB, bsr, bsi, out);
}

// Round 5
// 31.896 us; speedup vs baseline: 4.1078x; 1.1305x over previous
//
#include <hip/hip_runtime.h>
#include <hip/hip_bf16.h>

#define BB 4
#define NN 512
#define CC 32
#define KK 4      // K+1
#define HH 4
#define AOUT 256

// ws float-index offsets (si/sj)
#define WS_SI_F   0
#define WS_SII_F  (BB*NN*HH)
#define WS_SJR_F  (2*BB*NN*HH)
#define WS_SJI_F  (3*BB*NN*HH)
// ws byte offsets
#define XT_BASE   131072         // bf16 X tiles [part][b][jb16] x 2048 B
#define LX_BASE   393216         // bf16 LX [bn] x 2048 B   (4 MB)
#define BRE_BASE  4587520        // bf16 B_re fragments, 128 KB
#define BIM_BASE  4718592        // bf16 B_im fragments, 128 KB

typedef __attribute__((ext_vector_type(8))) short bf16x8;
typedef __attribute__((ext_vector_type(4))) float f32x4;

__device__ __forceinline__ ushort f2bfu(float f){
    union { __hip_bfloat16 h; ushort u; } cv;
    cv.h = __float2bfloat16(f);
    return cv.u;
}
__device__ __forceinline__ short f2bfs(float f){ return (short)f2bfu(f); }
__device__ __forceinline__ float bfu2f(unsigned int u){ return __uint_as_float(u << 16); }

// ---------------------------------------------------------------------------
// Fused prep kernel: grid 72 x 256
//  blk 0..7   : si/sj attention projections
//  blk 8..39  : pack X -> bf16 tiles (tile 32j x 32c = 2 KB; byte = c*64+(j&31)*2)
//  blk 40..71 : pack W -> B-fragment layout for out GEMM
// ---------------------------------------------------------------------------
__global__ __launch_bounds__(256) void prep_kernel(
    const float* __restrict__ Xr, const float* __restrict__ Xi,
    const float* __restrict__ AWr, const float* __restrict__ AWi,
    const float* __restrict__ Wr, const float* __restrict__ Wi,
    float* __restrict__ ws, char* __restrict__ wsB)
{
    const int blk = blockIdx.x;
    const int t = threadIdx.x;

    if (blk < 8) {
        int idx = blk*256 + t;
        const float* xr = Xr + (size_t)idx * CC;
        const float* xi = Xi + (size_t)idx * CC;
        float sir[HH] = {0,0,0,0}, sii[HH] = {0,0,0,0};
        float sjr[HH] = {0,0,0,0}, sji[HH] = {0,0,0,0};
        for (int c = 0; c < CC; ++c) {
            float xrc = xr[c], xic = xi[c];
            const float* w1r = AWr + c*HH;
            const float* w1i = AWi + c*HH;
            const float* w2r = AWr + (CC + c)*HH;
            const float* w2i = AWi + (CC + c)*HH;
            #pragma unroll
            for (int h = 0; h < HH; ++h) {
                sir[h] = fmaf(xrc, w1r[h], fmaf(-xic, w1i[h], sir[h]));
                sii[h] = fmaf(xrc, w1i[h], fmaf( xic, w1r[h], sii[h]));
                sjr[h] = fmaf(xrc, w2r[h], fmaf(-xic, w2i[h], sjr[h]));
                sji[h] = fmaf(xrc, w2i[h], fmaf( xic, w2r[h], sji[h]));
            }
        }
        #pragma unroll
        for (int h = 0; h < HH; ++h) {
            ws[WS_SI_F  + idx*HH + h] = sir[h];
            ws[WS_SII_F + idx*HH + h] = sii[h];
            ws[WS_SJR_F + idx*HH + h] = sjr[h];
            ws[WS_SJI_F + idx*HH + h] = sji[h];
        }
    } else if (blk < 40) {
        int bid = (blk - 8)*4 + (t >> 6);    // 0..127: part*64 + b*16 + jb
        int part = bid >> 6, b = (bid >> 4) & 3, jb = bid & 15;
        const float* X = part ? Xi : Xr;
        int lane = t & 63;
        int c = lane & 31, jh = lane >> 5;

        unsigned int w[8];
        #pragma unroll
        for (int q = 0; q < 8; ++q) {
            int ji = jh*16 + q*2;
            float f0 = X[((size_t)b*NN + jb*32 + ji  )*CC + c];
            float f1 = X[((size_t)b*NN + jb*32 + ji+1)*CC + c];
            w[q] = (unsigned int)f2bfu(f0) | ((unsigned int)f2bfu(f1) << 16);
        }
        char* tile = wsB + XT_BASE + (((size_t)(part*4 + b)*16 + jb) * 2048);
        uint4* dst = (uint4*)(tile + c*64 + jh*32);
        dst[0] = make_uint4(w[0], w[1], w[2], w[3]);
        dst[1] = make_uint4(w[4], w[5], w[6], w[7]);
    } else {
        // W fragment pack: idx over [h][Nt][s][lane]
        int idx = (blk - 40)*256 + t;        // 0..8191
        int l  = idx & 63;
        int s  = (idx >> 6) & 7;
        int Nt = (idx >> 9) & 3;
        int h  = idx >> 11;
        int p = Nt*16 + (l & 15), o = p*4 + h;
        int e8 = (l >> 4) * 8;
        unsigned int re_w[4], im_w[4];
        #pragma unroll
        for (int q = 0; q < 4; ++q) {
            unsigned int rw = 0, iw = 0;
            #pragma unroll
            for (int half = 0; half < 2; ++half) {
                int kpos = s*32 + e8 + q*2 + half;
                int ri = kpos >> 7, kk = (kpos >> 5) & 3, c = kpos & 31;
                float wr = Wr[(size_t)(kk*CC + c)*AOUT + o];
                float wi = Wi[(size_t)(kk*CC + c)*AOUT + o];
                unsigned int vre = f2bfu(ri ? -wi : wr);
                unsigned int vim = f2bfu(ri ?  wr : wi);
                rw |= vre << (16*half);
                iw |= vim << (16*half);
            }
            re_w[q] = rw; im_w[q] = iw;
        }
        size_t fo = ((size_t)((h*4 + Nt)*8 + s))*1024 + (size_t)l*16;
        *(uint4*)(wsB + BRE_BASE + fo) = make_uint4(re_w[0], re_w[1], re_w[2], re_w[3]);
        *(uint4*)(wsB + BIM_BASE + fo) = make_uint4(im_w[0], im_w[1], im_w[2], im_w[3]);
    }
}

// ---------------------------------------------------------------------------
// Main kernel: one block per (b,n), 128 threads (2 waves). LDS ~17 KB.
//  P1: L fp32 -> bf16 LDS; thread t sees ALL 8 rows at j=4t..4t+3 -> reg mask
//  P2: scores in registers (si/sj hoisted); exp from regs; float4 awf writes
//  P3: MFMA, 2-deep software-pipelined B-fragment loads, fully unrolled
//  reduce: single pbuf round; w0 writes normalized LX bf16
// ---------------------------------------------------------------------------
__global__ __launch_bounds__(128) void cheb_main_kernel(
    const float* __restrict__ Lr_g, const float* __restrict__ Li_g,
    const float* __restrict__ abr, const float* __restrict__ abi,
    const float* __restrict__ par, const float* __restrict__ pai,
    const float* __restrict__ ws, char* __restrict__ wsB)
{
    __shared__ ushort Lf[8][528];      // bf16 bits; 8448 B (rows: part*4+k)
    __shared__ float awf[HH][520];     // 8320 B; reused as pbuf (2048 floats)
    __shared__ float wredm[2][HH];
    __shared__ float wreds[2][HH];

    const int bn = blockIdx.x;
    const int b = bn >> 9;
    const int n = bn & (NN - 1);
    const int t = threadIdx.x;
    const int l = t & 63;
    const int w = t >> 6;
    const int jw = 4*t;                // this thread's j-window (P1/P2)

    // ---- hoisted L2 loads: si, sj for j-window ----
    const float4 si_r4 = *(const float4*)(ws + WS_SI_F  + bn*HH);
    const float4 si_i4 = *(const float4*)(ws + WS_SII_F + bn*HH);
    float4 sjr[4], sji[4];
    #pragma unroll
    for (int e = 0; e < 4; ++e) {
        sjr[e] = *(const float4*)(ws + WS_SJR_F + ((size_t)b*NN + jw + e)*HH);
        sji[e] = *(const float4*)(ws + WS_SJI_F + ((size_t)b*NN + jw + e)*HH);
    }
    const float a_r = par[0], a_i = pai[0];

    // ---- P1: stage L as bf16; accumulate fp32 mask from Lr rows ----
    float am4[4] = {0.f,0.f,0.f,0.f};
    #pragma unroll
    for (int it = 0; it < 8; ++it) {
        const float* src = (it & 4) ? Li_g : Lr_g;
        size_t goff = (((size_t)b*KK + (it & 3))*NN + n)*NN + jw;
        float4 v = *(const float4*)(src + goff);
        if (it < 4) {
            am4[0] += fabsf(v.x); am4[1] += fabsf(v.y);
            am4[2] += fabsf(v.z); am4[3] += fabsf(v.w);
        }
        ushort4 u;
        u.x = f2bfu(v.x); u.y = f2bfu(v.y); u.z = f2bfu(v.z); u.w = f2bfu(v.w);
        *(ushort4*)&Lf[it][jw] = u;
    }

    // ---- P2a: scores in registers ----
    float sir[HH], sii[HH];
    #pragma unroll
    for (int h = 0; h < HH; ++h) {
        sir[h] = ((const float*)&si_r4)[h] + abr[h];
        sii[h] = ((const float*)&si_i4)[h] + abi[h];
    }
    float v[4][HH];
    float pmax[HH] = {-INFINITY, -INFINITY, -INFINITY, -INFINITY};
    #pragma unroll
    for (int e = 0; e < 4; ++e) {
        bool msk = am4[e] > 1e-9f;
        const float* sjrp = (const float*)&sjr[e];
        const float* sjip = (const float*)&sji[e];
        #pragma unroll
        for (int h = 0; h < HH; ++h) {
            float sr = sir[h] + sjrp[h];
            sr = sr >= 0.f ? sr : a_r * sr;
            float sv = sii[h] + sjip[h];
            sv = sv >= 0.f ? sv : a_i * sv;
            float val;
            if (msk) val = sr*sr + sv*sv;
            else { const float NEG = -1e9f; val = NEG*NEG + NEG*NEG; }
            v[e][h] = val;
            pmax[h] = fmaxf(pmax[h], val);
        }
    }
    #pragma unroll
    for (int h = 0; h < HH; ++h) {
        #pragma unroll
        for (int off = 32; off > 0; off >>= 1)
            pmax[h] = fmaxf(pmax[h], __shfl_xor(pmax[h], off));
    }
    if (l == 0) { wredm[w][0]=pmax[0]; wredm[w][1]=pmax[1]; wredm[w][2]=pmax[2]; wredm[w][3]=pmax[3]; }
    __syncthreads();                   // S1: Lf + wredm visible

    float hm[HH];
    #pragma unroll
    for (int h = 0; h < HH; ++h) hm[h] = fmaxf(wredm[0][h], wredm[1][h]);

    // ---- P2b: exp from registers, float4 awf writes ----
    float psum[HH];
    #pragma unroll
    for (int h = 0; h < HH; ++h) {
        float4 ev;
        ev.x = __expf(v[0][h] - hm[h]);
        ev.y = __expf(v[1][h] - hm[h]);
        ev.z = __expf(v[2][h] - hm[h]);
        ev.w = __expf(v[3][h] - hm[h]);
        *(float4*)&awf[h][jw] = ev;
        psum[h] = (ev.x + ev.y) + (ev.z + ev.w);
    }
    #pragma unroll
    for (int h = 0; h < HH; ++h) {
        #pragma unroll
        for (int off = 32; off > 0; off >>= 1)
            psum[h] += __shfl_xor(psum[h], off);
    }
    if (l == 0) { wreds[w][0]=psum[0]; wreds[w][1]=psum[1]; wreds[w][2]=psum[2]; wreds[w][3]=psum[3]; }
    __syncthreads();                   // S2: awf + wreds visible

    float inv[HH];
    #pragma unroll
    for (int h = 0; h < HH; ++h) inv[h] = 1.0f / (wreds[0][h] + wreds[1][h]);

    // ---- P3: MFMA, wave w owns j in [w*256, w*256+256), 8 steps, 2-deep pipe ----
    const int r_a = l & 15;            // A row = k*4+h
    const int jg  = l >> 4;
    const int k_a = r_a >> 2, h_a = r_a & 3;

    f32x4 acc[8];                      // RR0 RR1 II0 II1 RI0 RI1 IR0 IR1
    #pragma unroll
    for (int a = 0; a < 8; ++a) acc[a] = (f32x4){0.f,0.f,0.f,0.f};

    const char* xtR = wsB + XT_BASE + ((size_t)(0*4 + b)*16 + w*8)*2048;
    const char* xtI = wsB + XT_BASE + ((size_t)(4   + b)*16 + w*8)*2048;
    const int bofs = (l & 15)*64 + jg*16;

#define LOAD_STEP(s, BR0,BR1,BI0,BI1, LR8,LI8, AW0,AW1) do {                  \
        const int j0_ = w*256 + (s)*32 + jg*8;                                \
        BR0 = *(const bf16x8*)(xtR + (s)*2048 +        bofs);                 \
        BR1 = *(const bf16x8*)(xtR + (s)*2048 + 1024 + bofs);                 \
        BI0 = *(const bf16x8*)(xtI + (s)*2048 +        bofs);                 \
        BI1 = *(const bf16x8*)(xtI + (s)*2048 + 1024 + bofs);                 \
        LR8 = *(const bf16x8*)&Lf[k_a][j0_];                                  \
        LI8 = *(const bf16x8*)&Lf[4 + k_a][j0_];                              \
        AW0 = *(const float4*)&awf[h_a][j0_];                                 \
        AW1 = *(const float4*)&awf[h_a][j0_ + 4];                             \
    } while (0)

#define COMP_STEP(BR0,BR1,BI0,BI1, LR8,LI8, AW0,AW1) do {                     \
        float aww_[8];                                                        \
        *(float4*)&aww_[0] = AW0; *(float4*)&aww_[4] = AW1;                   \
        bf16x8 Ar_, Ai_;                                                      \
        _Pragma("unroll")                                                     \
        for (int e_ = 0; e_ < 8; ++e_) {                                      \
            Ar_[e_] = f2bfs(bfu2f((ushort)LR8[e_]) * aww_[e_]);               \
            Ai_[e_] = f2bfs(bfu2f((ushort)LI8[e_]) * aww_[e_]);               \
        }                                                                     \
        acc[0] = __builtin_amdgcn_mfma_f32_16x16x32_bf16(Ar_, BR0, acc[0],0,0,0); \
        acc[1] = __builtin_amdgcn_mfma_f32_16x16x32_bf16(Ar_, BR1, acc[1],0,0,0); \
        acc[2] = __builtin_amdgcn_mfma_f32_16x16x32_bf16(Ai_, BI0, acc[2],0,0,0); \
        acc[3] = __builtin_amdgcn_mfma_f32_16x16x32_bf16(Ai_, BI1, acc[3],0,0,0); \
        acc[4] = __builtin_amdgcn_mfma_f32_16x16x32_bf16(Ar_, BI0, acc[4],0,0,0); \
        acc[5] = __builtin_amdgcn_mfma_f32_16x16x32_bf16(Ar_, BI1, acc[5],0,0,0); \
        acc[6] = __builtin_amdgcn_mfma_f32_16x16x32_bf16(Ai_, BR0, acc[6],0,0,0); \
        acc[7] = __builtin_amdgcn_mfma_f32_16x16x32_bf16(Ai_, BR1, acc[7],0,0,0); \
    } while (0)

    {
        bf16x8 pBr0,pBr1,pBi0,pBi1,pLr,pLi; float4 pA0,pA1;
        bf16x8 qBr0,qBr1,qBi0,qBi1,qLr,qLi; float4 qA0,qA1;
        LOAD_STEP(0, pBr0,pBr1,pBi0,pBi1, pLr,pLi, pA0,pA1);
        LOAD_STEP(1, qBr0,qBr1,qBi0,qBi1, qLr,qLi, qA0,qA1);
        COMP_STEP(pBr0,pBr1,pBi0,pBi1, pLr,pLi, pA0,pA1);
        LOAD_STEP(2, pBr0,pBr1,pBi0,pBi1, pLr,pLi, pA0,pA1);
        COMP_STEP(qBr0,qBr1,qBi0,qBi1, qLr,qLi, qA0,qA1);
        LOAD_STEP(3, qBr0,qBr1,qBi0,qBi1, qLr,qLi, qA0,qA1);
        COMP_STEP(pBr0,pBr1,pBi0,pBi1, pLr,pLi, pA0,pA1);
        LOAD_STEP(4, pBr0,pBr1,pBi0,pBi1, pLr,pLi, pA0,pA1);
        COMP_STEP(qBr0,qBr1,qBi0,qBi1, qLr,qLi, qA0,qA1);
        LOAD_STEP(5, qBr0,qBr1,qBi0,qBi1, qLr,qLi, qA0,qA1);
        COMP_STEP(pBr0,pBr1,pBi0,pBi1, pLr,pLi, pA0,pA1);
        LOAD_STEP(6, pBr0,pBr1,pBi0,pBi1, pLr,pLi, pA0,pA1);
        COMP_STEP(qBr0,qBr1,qBi0,qBi1, qLr,qLi, qA0,qA1);
        LOAD_STEP(7, qBr0,qBr1,qBi0,qBi1, qLr,qLi, qA0,qA1);
        COMP_STEP(pBr0,pBr1,pBi0,pBi1, pLr,pLi, pA0,pA1);
        COMP_STEP(qBr0,qBr1,qBi0,qBi1, qLr,qLi, qA0,qA1);
    }
#undef LOAD_STEP
#undef COMP_STEP

    __syncthreads();                   // S3: all awf/Lf reads done

    float* pbuf = &awf[0][0];
    if (w == 1) {
        #pragma unroll
        for (int a = 0; a < 8; ++a)
            #pragma unroll
            for (int r = 0; r < 4; ++r)
                pbuf[(a*4 + r)*64 + l] = acc[a][r];
    }
    __syncthreads();                   // S4
    if (w == 0) {
        const int kk = l >> 4, lc = l & 15;
        #pragma unroll
        for (int a = 0; a < 8; ++a)
            #pragma unroll
            for (int r = 0; r < 4; ++r)
                acc[a][r] += pbuf[(a*4 + r)*64 + l];
        // LX bf16: [bn](2048B) layout [h(r)][ri][k][c]
        char* lxp = wsB + LX_BASE + (size_t)bn*2048;
        #pragma unroll
        for (int ct = 0; ct < 2; ++ct) {
            const int c = ct*16 + lc;
            #pragma unroll
            for (int r = 0; r < 4; ++r) {   // r == h
                float iv = inv[r];
                float vr = (acc[0+ct][r] - acc[2+ct][r]) * iv;
                float vi = (acc[4+ct][r] + acc[6+ct][r]) * iv;
                *(ushort*)(lxp + r*512 +       kk*64 + c*2) = f2bfu(vr);
                *(ushort*)(lxp + r*512 + 256 + kk*64 + c*2) = f2bfu(vi);
            }
        }
    }
}

// ---------------------------------------------------------------------------
// Out GEMM: Y[bn,o] = [LXr|LXi] @ Bre/Bim (K=256), + bias.
// grid 512 blocks (Mtile*4 + Nt) x 256 thr; wave = h.
// ---------------------------------------------------------------------------
__global__ __launch_bounds__(256) void out_gemm_kernel(
    const char* __restrict__ wsB,
    const float* __restrict__ bsr, const float* __restrict__ bsi,
    float* __restrict__ out)
{
    const int Mtile = blockIdx.x >> 2;
    const int Nt    = blockIdx.x & 3;
    const int t = threadIdx.x, l = t & 63, h = t >> 6;

    const char* abase = wsB + LX_BASE + ((size_t)(Mtile*16 + (l & 15)))*2048
                        + h*512 + (l >> 4)*16;
    f32x4 are = (f32x4){0.f,0.f,0.f,0.f};
    f32x4 aim = (f32x4){0.f,0.f,0.f,0.f};
    const size_t fbase = ((size_t)((h*4 + Nt)*8))*1024 + (size_t)l*16;
    const char* bre = wsB + BRE_BASE + fbase;
    const char* bim = wsB + BIM_BASE + fbase;
    #pragma unroll
    for (int s = 0; s < 8; ++s) {
        bf16x8 Af = *(const bf16x8*)(abase + s*64);
        bf16x8 Br = *(const bf16x8*)(bre + s*1024);
        bf16x8 Bi = *(const bf16x8*)(bim + s*1024);
        are = __builtin_amdgcn_mfma_f32_16x16x32_bf16(Af, Br, are, 0, 0, 0);
        aim = __builtin_amdgcn_mfma_f32_16x16x32_bf16(Af, Bi, aim, 0, 0, 0);
    }
    const int p = Nt*16 + (l & 15), o = p*4 + h;
    const float vbr = bsr[o], vbi = bsi[o];
    #pragma unroll
    for (int r = 0; r < 4; ++r) {
        int bn = Mtile*16 + (l >> 4)*4 + r;
        out[(size_t)bn*AOUT + o] = are[r] + vbr;
        out[(size_t)BB*NN*AOUT + (size_t)bn*AOUT + o] = aim[r] + vbi;
    }
}

// ---------------------------------------------------------------------------
extern "C" void kernel_launch(void* const* d_in, const int* in_sizes, int n_in,
                              void* d_out, int out_size, void* d_ws, size_t ws_size,
                              hipStream_t stream)
{
    const float* Xr  = (const float*)d_in[0];
    const float* Xi  = (const float*)d_in[1];
    const float* Lr  = (const float*)d_in[2];
    const float* Li  = (const float*)d_in[3];
    const float* Wr  = (const float*)d_in[4];
    const float* Wi  = (const float*)d_in[5];
    const float* AWr = (const float*)d_in[6];
    const float* AWi = (const float*)d_in[7];
    const float* abr = (const float*)d_in[8];
    const float* abi = (const float*)d_in[9];
    const float* par = (const float*)d_in[10];
    const float* pai = (const float*)d_in[11];
    const float* bsr = (const float*)d_in[12];
    const float* bsi = (const float*)d_in[13];
    float* ws  = (float*)d_ws;
    char*  wsB = (char*)d_ws;
    float* out = (float*)d_out;

    hipLaunchKernelGGL(prep_kernel, dim3(72), dim3(256), 0, stream,
                       Xr, Xi, AWr, AWi, Wr, Wi, ws, wsB);
    hipLaunchKernelGGL(cheb_main_kernel, dim3(BB*NN), dim3(128), 0, stream,
                       Lr, Li, abr, abi, par, pai, ws, wsB);
    hipLaunchKernelGGL(out_gemm_kernel, dim3(512), dim3(256), 0, stream,
                       wsB, bsr, bsi, out);
}